// Round 8
// baseline (593.763 us; speedup 1.0000x reference)
//
#include <hip/hip_runtime.h>
#include <math.h>

// Problem constants
#define Bq 16
#define Cc 256
#define HW 4096      // H*W
#define Mm 512
#define Nn 65536     // B*H*W
#define Oo 256
#define Kf 768       // fused conv K = C (qnorm) + M (P)

typedef short bf16x8 __attribute__((ext_vector_type(8)));
typedef float f32x4 __attribute__((ext_vector_type(4)));
typedef unsigned short ushort_t;

__device__ __forceinline__ unsigned int bf16rne(float f) {
  unsigned int u = __float_as_uint(f);
  return (u + 0x7FFFu + ((u >> 16) & 1u)) >> 16;   // RNE bf16 bits
}
__device__ __forceinline__ float bf16f(unsigned int h) { return __uint_as_float(h << 16); }
// split pair of fp32 into packed bf16 hi and bf16 lo words
__device__ __forceinline__ void split2(float v0, float v1,
                                       unsigned int& hi, unsigned int& lo) {
  unsigned int h0 = bf16rne(v0), h1 = bf16rne(v1);
  hi = h0 | (h1 << 16);
  unsigned int l0 = bf16rne(v0 - bf16f(h0)), l1 = bf16rne(v1 - bf16f(h1));
  lo = l0 | (l1 << 16);
}

// ---------------------------------------------------------------- k_qt:
//  blocks [0,2048):    transpose query, fp32 norm, emit qnorm hi/lo bf16 [N][C]
//  blocks [2048,2056): cvt mem -> memT bf16 [M][C]
__global__ __launch_bounds__(256) void k_qt(const float* __restrict__ query,
                                            ushort_t* __restrict__ qhiT,
                                            ushort_t* __restrict__ qloT,
                                            const float* __restrict__ mem,
                                            ushort_t* __restrict__ memT) {
  __shared__ float T[256][36];   // 256 channels x 32 pixels, padded
  __shared__ float S2[8][32];
  __shared__ float invn_s[32];
  int tid = threadIdx.x, bid = blockIdx.x;
  if (bid < 2048) {
    int n0 = bid * 32;
    int b = n0 >> 12, hw0 = n0 & 4095;
    const float* qb = query + (size_t)b * Cc * HW + hw0;
#pragma unroll
    for (int p = 0; p < 8; ++p) {
      int idx = p * 256 + tid;
      int c = idx >> 3, f4 = idx & 7;
      float4 v = *(const float4*)(qb + (size_t)c * HW + f4 * 4);
      *(float4*)&T[c][f4 * 4] = v;
    }
    __syncthreads();
    {
      int n = tid & 31, cq = tid >> 5;
      float s = 0.f;
#pragma unroll
      for (int c = 0; c < 32; ++c) { float v = T[cq * 32 + c][n]; s += v * v; }
      S2[cq][n] = s;
    }
    __syncthreads();
    if (tid < 32) {
      float s = 0.f;
#pragma unroll
      for (int q = 0; q < 8; ++q) s += S2[q][tid];
      invn_s[tid] = 1.f / fmaxf(sqrtf(s), 1e-12f);
    }
    __syncthreads();
#pragma unroll
    for (int p = 0; p < 4; ++p) {
      int idx = p * 256 + tid;
      int n = idx & 31, g = idx >> 5;          // granule g = 8 channels
      float ivn = invn_s[n];
      unsigned int hv[4], lv[4];
#pragma unroll
      for (int h = 0; h < 4; ++h) {
        int c0 = g * 8 + h * 2;
        split2(T[c0][n] * ivn, T[c0 + 1][n] * ivn, hv[h], lv[h]);
      }
      *(uint4*)(qhiT + (size_t)(n0 + n) * 256 + g * 8) = make_uint4(hv[0], hv[1], hv[2], hv[3]);
      *(uint4*)(qloT + (size_t)(n0 + n) * 256 + g * 8) = make_uint4(lv[0], lv[1], lv[2], lv[3]);
    }
  } else {
    int r0 = (bid - 2048) * 64;
#pragma unroll
    for (int p = 0; p < 8; ++p) {
      int idx = p * 256 + tid;
      int row = idx >> 5, g = idx & 31;
      const float* src = mem + (size_t)(r0 + row) * 256 + g * 8;
      float4 a = *(const float4*)(src);
      float4 c = *(const float4*)(src + 4);
      unsigned int w0 = bf16rne(a.x) | (bf16rne(a.y) << 16);
      unsigned int w1 = bf16rne(a.z) | (bf16rne(a.w) << 16);
      unsigned int w2 = bf16rne(c.x) | (bf16rne(c.y) << 16);
      unsigned int w3 = bf16rne(c.z) | (bf16rne(c.w) << 16);
      *(uint4*)(memT + (size_t)(r0 + row) * 256 + g * 8) = make_uint4(w0, w1, w2, w3);
    }
  }
}

// ---------------------------------------------------------------- k_wm: build W' = [Wq | Wc@mem^T] split hi/lo [256][768]
//  blocks 0..7:  Wm GEMM tiles (fp32) -> split -> Ahi/Alo[:, 256:768]
//  blocks 8..15: Wq elementwise split  -> Ahi/Alo[:, 0:256]
__global__ __launch_bounds__(256) void k_wm(const float* __restrict__ conv_w,
                                            const float* __restrict__ mem,
                                            ushort_t* __restrict__ Ahi,
                                            ushort_t* __restrict__ Alo) {
  __shared__ __align__(16) float Asm[16 * 132];
  __shared__ __align__(16) float Bsm[16 * 132];
  int tid = threadIdx.x, bid = blockIdx.x;
  if (bid >= 8) {
    int b8 = bid - 8;
#pragma unroll
    for (int p = 0; p < 8; ++p) {
      int idx = b8 * 2048 + p * 256 + tid;     // 16384 float4 over 256x256
      int o = idx >> 6, c4 = (idx & 63) * 4;
      float4 v = *(const float4*)(conv_w + (size_t)o * 512 + c4);
      unsigned int h0, l0, h1, l1;
      split2(v.x, v.y, h0, l0);
      split2(v.z, v.w, h1, l1);
      *(uint2*)(Ahi + (size_t)o * 768 + c4) = make_uint2(h0, h1);
      *(uint2*)(Alo + (size_t)o * 768 + c4) = make_uint2(l0, l1);
    }
    return;
  }
  int tile_o = bid & 1, tile_m = bid >> 1;
  int o0 = tile_o * 128, m0 = tile_m * 128;
  int tx = tid & 15, ty = tid >> 4;
  int akk = tid & 15, ao0 = tid >> 4;
  int bk = tid & 15, bm = tid >> 4;

  float acc[2][2][4][4];
#pragma unroll
  for (int a = 0; a < 2; ++a)
#pragma unroll
    for (int c = 0; c < 2; ++c)
#pragma unroll
      for (int i = 0; i < 4; ++i)
#pragma unroll
        for (int j = 0; j < 4; ++j) acc[a][c][i][j] = 0.f;

  for (int k0 = 0; k0 < Cc; k0 += 16) {
#pragma unroll
    for (int i = 0; i < 8; ++i) {
      int o = ao0 + i * 16;
      Asm[akk * 132 + o] = conv_w[(size_t)(o0 + o) * 512 + 256 + k0 + akk];
    }
#pragma unroll
    for (int i = 0; i < 8; ++i) {
      int m = bm + i * 16;
      Bsm[bk * 132 + m] = mem[(size_t)(m0 + m) * Cc + k0 + bk];
    }
    __syncthreads();
#pragma unroll
    for (int kk = 0; kk < 16; ++kk) {
      float4 a0 = *(const float4*)&Asm[kk * 132 + ty * 4];
      float4 a1 = *(const float4*)&Asm[kk * 132 + 64 + ty * 4];
      float4 b0 = *(const float4*)&Bsm[kk * 132 + tx * 4];
      float4 b1 = *(const float4*)&Bsm[kk * 132 + 64 + tx * 4];
      float av[2][4] = {{a0.x, a0.y, a0.z, a0.w}, {a1.x, a1.y, a1.z, a1.w}};
      float bv[2][4] = {{b0.x, b0.y, b0.z, b0.w}, {b1.x, b1.y, b1.z, b1.w}};
#pragma unroll
      for (int ib = 0; ib < 2; ++ib)
#pragma unroll
        for (int i = 0; i < 4; ++i)
#pragma unroll
          for (int jb = 0; jb < 2; ++jb)
#pragma unroll
            for (int j = 0; j < 4; ++j) acc[ib][jb][i][j] += av[ib][i] * bv[jb][j];
    }
    __syncthreads();
  }
#pragma unroll
  for (int ib = 0; ib < 2; ++ib)
#pragma unroll
    for (int i = 0; i < 4; ++i) {
      int o = o0 + ib * 64 + ty * 4 + i;
#pragma unroll
      for (int jb = 0; jb < 2; ++jb) {
        int mc = m0 + jb * 64 + tx * 4;
        unsigned int h0, l0, h1, l1;
        split2(acc[ib][jb][i][0], acc[ib][jb][i][1], h0, l0);
        split2(acc[ib][jb][i][2], acc[ib][jb][i][3], h1, l1);
        *(uint2*)(Ahi + (size_t)o * 768 + 256 + mc) = make_uint2(h0, h1);
        *(uint2*)(Alo + (size_t)o * 768 + 256 + mc) = make_uint2(l0, l1);
      }
    }
}

// ---------------------------------------------------------------- G1 (MFMA bf16): exs = exp(qnorm.mem), row/col sums
__global__ __launch_bounds__(256) void k_score(const ushort_t* __restrict__ qhiT,
                                               const ushort_t* __restrict__ memT,
                                               float* __restrict__ exs,
                                               float* __restrict__ rowsum,
                                               float* __restrict__ colsum) {
  __shared__ ushort_t As[128 * 64];   // 16KB each, XOR-swizzled 16B granules
  __shared__ ushort_t Bs[128 * 64];
  int tid = threadIdx.x, bid = blockIdx.x;
  int m0 = (bid & 3) * 128;
  int n0 = (bid >> 2) * 128;
  int lane = tid & 63;
  int w = tid >> 6, wrow = w >> 1, wcol = w & 1;

  f32x4 acc[4][4];
#pragma unroll
  for (int i = 0; i < 4; ++i)
#pragma unroll
    for (int j = 0; j < 4; ++j)
#pragma unroll
      for (int e = 0; e < 4; ++e) acc[i][j][e] = 0.f;

  uint4* As4 = (uint4*)As;
  uint4* Bs4 = (uint4*)Bs;

  for (int kt = 0; kt < 4; ++kt) {
    int k0 = kt * 64;
#pragma unroll
    for (int p = 0; p < 4; ++p) {
      int idx = p * 256 + tid;
      int row = idx >> 3, g = idx & 7;
      int G = g ^ (row & 7);                 // T2 swizzle (write side)
      As4[row * 8 + G] = *(const uint4*)(qhiT + (size_t)(n0 + row) * 256 + k0 + g * 8);
      Bs4[row * 8 + G] = *(const uint4*)(memT + (size_t)(m0 + row) * 256 + k0 + g * 8);
    }
    __syncthreads();
#pragma unroll
    for (int ks = 0; ks < 2; ++ks) {
      bf16x8 a[4], b[4];
#pragma unroll
      for (int i = 0; i < 4; ++i) {
        int row = wrow * 64 + i * 16 + (lane & 15);
        int G = ((lane >> 4) + ks * 4) ^ (row & 7);   // same swizzle (read side)
        a[i] = ((const bf16x8*)As)[row * 8 + G];
      }
#pragma unroll
      for (int j = 0; j < 4; ++j) {
        int row = wcol * 64 + j * 16 + (lane & 15);
        int G = ((lane >> 4) + ks * 4) ^ (row & 7);
        b[j] = ((const bf16x8*)Bs)[row * 8 + G];
      }
#pragma unroll
      for (int i = 0; i < 4; ++i)
#pragma unroll
        for (int j = 0; j < 4; ++j)
          acc[i][j] = __builtin_amdgcn_mfma_f32_16x16x32_bf16(a[i], b[j], acc[i][j], 0, 0, 0);
    }
    __syncthreads();
  }

  // epilogue: C/D map col=lane&15, row=(lane>>4)*4+reg  [m89-verified]
  float rp[4][4], cp[4];
#pragma unroll
  for (int i = 0; i < 4; ++i)
#pragma unroll
    for (int r = 0; r < 4; ++r) rp[i][r] = 0.f;
#pragma unroll
  for (int j = 0; j < 4; ++j) cp[j] = 0.f;

#pragma unroll
  for (int i = 0; i < 4; ++i) {
#pragma unroll
    for (int r = 0; r < 4; ++r) {
      int pl = wrow * 64 + i * 16 + (lane >> 4) * 4 + r;
      float* orow = exs + (size_t)(n0 + pl) * Mm + m0;
#pragma unroll
      for (int j = 0; j < 4; ++j) {
        int sl = wcol * 64 + j * 16 + (lane & 15);
        float e = __expf(acc[i][j][r]);      // |score|<=1: no max-shift needed
        orow[sl] = e;
        rp[i][r] += e;
        cp[j] += e;
      }
    }
  }

  float* red = (float*)As;   // 4096 floats
#pragma unroll
  for (int i = 0; i < 4; ++i)
#pragma unroll
    for (int r = 0; r < 4; ++r) {
      int pl = wrow * 64 + i * 16 + (lane >> 4) * 4 + r;
      red[pl * 32 + wcol * 16 + (lane & 15)] = rp[i][r];
    }
  __syncthreads();
  if (tid < 128) {
    float s = 0.f;
#pragma unroll
    for (int x = 0; x < 32; ++x) s += red[tid * 32 + x];
    atomicAdd(&rowsum[n0 + tid], s);
  }
  __syncthreads();
#pragma unroll
  for (int j = 0; j < 4; ++j) {
    int sl = wcol * 64 + j * 16 + (lane & 15);
    red[sl * 8 + wrow * 4 + (lane >> 4)] = cp[j];
  }
  __syncthreads();
  if (tid < 128) {
    float s = 0.f;
#pragma unroll
    for (int x = 0; x < 8; ++x) s += red[tid * 8 + x];
    atomicAdd(&colsum[m0 + tid], s);
  }
}

// ---------------------------------------------------------------- fused conv (split-bf16 MFMA): y = W' @ X^T, K=768
// X[n][k] = qnorm (k<256, precomputed hi/lo) | P = exs*invrow (k>=256, split on the fly)
__global__ __launch_bounds__(256) void k_conv(const ushort_t* __restrict__ Ahi,
                                              const ushort_t* __restrict__ Alo,
                                              const ushort_t* __restrict__ qhiT,
                                              const ushort_t* __restrict__ qloT,
                                              const float* __restrict__ exs,
                                              const float* __restrict__ rowsum,
                                              float* __restrict__ y,
                                              float* __restrict__ bnsum,
                                              float* __restrict__ bnsumsq) {
  __shared__ ushort_t AsH[128 * 64], AsL[128 * 64];
  __shared__ ushort_t BsH[128 * 64], BsL[128 * 64];
  __shared__ float irow[128];
  int tid = threadIdx.x, bid = blockIdx.x;
  int tile_o = bid & 1, tile_n = bid >> 1;
  int o0 = tile_o * 128, n0 = tile_n * 128;
  int b = n0 >> 12, hw0 = n0 & 4095;
  if (tid < 128) irow[tid] = 1.0f / rowsum[n0 + tid];
  int lane = tid & 63;
  int w = tid >> 6, wrow = w >> 1, wcol = w & 1;

  f32x4 acc[4][4];
#pragma unroll
  for (int i = 0; i < 4; ++i)
#pragma unroll
    for (int j = 0; j < 4; ++j)
#pragma unroll
      for (int e = 0; e < 4; ++e) acc[i][j][e] = 0.f;

  uint4* AsH4 = (uint4*)AsH;
  uint4* AsL4 = (uint4*)AsL;
  uint4* BsH4 = (uint4*)BsH;
  uint4* BsL4 = (uint4*)BsL;
  uint2* BsH2 = (uint2*)BsH;
  uint2* BsL2 = (uint2*)BsL;
  __syncthreads();   // irow visible to all before any k>=256 staging

  for (int kt = 0; kt < 12; ++kt) {
    int k0 = kt * 64;
    // A staging: W' tile [128 o][64 k], hi+lo
#pragma unroll
    for (int p = 0; p < 4; ++p) {
      int idx = p * 256 + tid;
      int row = idx >> 3, g = idx & 7;
      int G = g ^ (row & 7);
      size_t src = (size_t)(o0 + row) * 768 + k0 + g * 8;
      AsH4[row * 8 + G] = *(const uint4*)(Ahi + src);
      AsL4[row * 8 + G] = *(const uint4*)(Alo + src);
    }
    if (k0 < 256) {
      // B staging: qnorm hi/lo copies [128 n][64 k]
#pragma unroll
      for (int p = 0; p < 4; ++p) {
        int idx = p * 256 + tid;
        int row = idx >> 3, g = idx & 7;
        int G = g ^ (row & 7);
        size_t src = (size_t)(n0 + row) * 256 + k0 + g * 8;
        BsH4[row * 8 + G] = *(const uint4*)(qhiT + src);
        BsL4[row * 8 + G] = *(const uint4*)(qloT + src);
      }
    } else {
      // B staging: P = exs * irow, split on the fly
#pragma unroll
      for (int p = 0; p < 8; ++p) {
        int idx = p * 256 + tid;
        int row = idx >> 4, f4 = idx & 15;       // 16 float4 per row
        float ir = irow[row];
        float4 v = *(const float4*)(exs + (size_t)(n0 + row) * Mm + (k0 - 256) + f4 * 4);
        unsigned int h0, l0, h1, l1;
        split2(v.x * ir, v.y * ir, h0, l0);
        split2(v.z * ir, v.w * ir, h1, l1);
        int g = f4 >> 1, half = f4 & 1;
        int G = g ^ (row & 7);
        BsH2[(row * 8 + G) * 2 + half] = make_uint2(h0, h1);
        BsL2[(row * 8 + G) * 2 + half] = make_uint2(l0, l1);
      }
    }
    __syncthreads();
#pragma unroll
    for (int ks = 0; ks < 2; ++ks) {
      bf16x8 ah[4], al[4], bh[4], bl[4];
#pragma unroll
      for (int i = 0; i < 4; ++i) {
        int row = wrow * 64 + i * 16 + (lane & 15);
        int G = ((lane >> 4) + ks * 4) ^ (row & 7);
        ah[i] = ((const bf16x8*)AsH)[row * 8 + G];
        al[i] = ((const bf16x8*)AsL)[row * 8 + G];
      }
#pragma unroll
      for (int j = 0; j < 4; ++j) {
        int row = wcol * 64 + j * 16 + (lane & 15);
        int G = ((lane >> 4) + ks * 4) ^ (row & 7);
        bh[j] = ((const bf16x8*)BsH)[row * 8 + G];
        bl[j] = ((const bf16x8*)BsL)[row * 8 + G];
      }
#pragma unroll
      for (int i = 0; i < 4; ++i)
#pragma unroll
        for (int j = 0; j < 4; ++j) {
          acc[i][j] = __builtin_amdgcn_mfma_f32_16x16x32_bf16(al[i], bh[j], acc[i][j], 0, 0, 0);
          acc[i][j] = __builtin_amdgcn_mfma_f32_16x16x32_bf16(ah[i], bl[j], acc[i][j], 0, 0, 0);
          acc[i][j] = __builtin_amdgcn_mfma_f32_16x16x32_bf16(ah[i], bh[j], acc[i][j], 0, 0, 0);
        }
    }
    __syncthreads();
  }

  // epilogue: y store + BN partial sums (C/D map: col=lane&15, row=(lane>>4)*4+r)
  float rp[4][4], rq[4][4];
#pragma unroll
  for (int i = 0; i < 4; ++i)
#pragma unroll
    for (int r = 0; r < 4; ++r) { rp[i][r] = 0.f; rq[i][r] = 0.f; }

#pragma unroll
  for (int i = 0; i < 4; ++i) {
#pragma unroll
    for (int r = 0; r < 4; ++r) {
      int pl = wrow * 64 + i * 16 + (lane >> 4) * 4 + r;   // o within tile
      float* orow = y + (size_t)b * Oo * HW + (size_t)(o0 + pl) * HW + hw0;
#pragma unroll
      for (int j = 0; j < 4; ++j) {
        int sl = wcol * 64 + j * 16 + (lane & 15);          // n within tile
        float v = acc[i][j][r];
        orow[sl] = v;
        rp[i][r] += v;
        rq[i][r] += v * v;
      }
    }
  }

  float* red = (float*)AsH;   // 4096 floats
#pragma unroll
  for (int i = 0; i < 4; ++i)
#pragma unroll
    for (int r = 0; r < 4; ++r) {
      int pl = wrow * 64 + i * 16 + (lane >> 4) * 4 + r;
      red[pl * 32 + wcol * 16 + (lane & 15)] = rp[i][r];
    }
  __syncthreads();
  if (tid < 128) {
    float s = 0.f;
#pragma unroll
    for (int x = 0; x < 32; ++x) s += red[tid * 32 + x];
    atomicAdd(&bnsum[o0 + tid], s);
  }
  __syncthreads();
#pragma unroll
  for (int i = 0; i < 4; ++i)
#pragma unroll
    for (int r = 0; r < 4; ++r) {
      int pl = wrow * 64 + i * 16 + (lane >> 4) * 4 + r;
      red[pl * 32 + wcol * 16 + (lane & 15)] = rq[i][r];
    }
  __syncthreads();
  if (tid < 128) {
    float s = 0.f;
#pragma unroll
    for (int x = 0; x < 32; ++x) s += red[tid * 32 + x];
    atomicAdd(&bnsumsq[o0 + tid], s);
  }
}

// ---------------------------------------------------------------- merged finisher
__global__ __launch_bounds__(256) void k_final(float4* __restrict__ y4,
                                               const float* __restrict__ bnsum,
                                               const float* __restrict__ bnsumsq,
                                               const float* __restrict__ gamma,
                                               const float* __restrict__ beta,
                                               float4* __restrict__ smm4,
                                               const float* __restrict__ rowsum,
                                               const float4* __restrict__ colsum4,
                                               float4* __restrict__ smq4) {
  int bid = blockIdx.x;
  if (bid < 16384) {
    int g = bid * 256 + threadIdx.x;
    int o = (g >> 10) & 255;
    float mean = bnsum[o] * (1.f / Nn);
    float var = bnsumsq[o] * (1.f / Nn) - mean * mean;
    float s = gamma[o] * rsqrtf(var + 1e-5f);
    float t = beta[o] - mean * s;
    float4 v = y4[g];
    v.x = fmaxf(v.x * s + t, 0.f);
    v.y = fmaxf(v.y * s + t, 0.f);
    v.z = fmaxf(v.z * s + t, 0.f);
    v.w = fmaxf(v.w * s + t, 0.f);
    y4[g] = v;
  } else {
    int g = (bid - 16384) * 256 + threadIdx.x;
    int n = g >> 7;
    int c4 = g & 127;
    float4 e = smm4[g];
    float4 cs = colsum4[c4];
    float irn = 1.0f / rowsum[n];
    smq4[g] = make_float4(e.x / cs.x, e.y / cs.y, e.z / cs.z, e.w / cs.w);
    smm4[g] = make_float4(e.x * irn, e.y * irn, e.z * irn, e.w * irn);
  }
}

// ---------------------------------------------------------------- launch
extern "C" void kernel_launch(void* const* d_in, const int* in_sizes, int n_in,
                              void* d_out, int out_size, void* d_ws, size_t ws_size,
                              hipStream_t stream) {
  (void)in_sizes; (void)n_in; (void)out_size; (void)ws_size;
  const float* query  = (const float*)d_in[0];
  const float* mem    = (const float*)d_in[1];
  const float* conv_w = (const float*)d_in[2];
  const float* gamma  = (const float*)d_in[3];
  const float* beta   = (const float*)d_in[4];
  float* out = (float*)d_out;
  float* y   = out;                    // 16,777,216 floats
  float* smq = out + 16777216;         // 33,554,432 floats
  float* smm = smq + 33554432;         // 33,554,432 floats (exp matrix until k_final)
  // big scratch lives in the dead smq region (all consumed before k_final writes it)
  ushort_t* qhiT = (ushort_t*)smq;                    // [65536][256] bf16
  ushort_t* qloT = (ushort_t*)(smq + 8388608);        // [65536][256]
  ushort_t* memT = (ushort_t*)(smq + 16777216);       // [512][256]
  ushort_t* Ahi  = (ushort_t*)(smq + 16842752);       // [256][768]
  ushort_t* Alo  = (ushort_t*)(smq + 16941056);       // [256][768]
  float* ws = (float*)d_ws;
  float* rowsum  = ws;                 // 65536
  float* colsum  = ws + 65536;         // 512
  float* bnsum   = ws + 66048;         // 256
  float* bnsumsq = ws + 66304;         // 256

  hipMemsetAsync(ws, 0, 66560 * sizeof(float), stream);

  k_qt<<<2056, 256, 0, stream>>>(query, qhiT, qloT, mem, memT);
  k_wm<<<16, 256, 0, stream>>>(conv_w, mem, Ahi, Alo);
  k_score<<<2048, 256, 0, stream>>>(qhiT, memT, smm, rowsum, colsum);
  k_conv<<<1024, 256, 0, stream>>>(Ahi, Alo, qhiT, qloT, smm, rowsum,
                                   y, bnsum, bnsumsq);
  k_final<<<49152, 256, 0, stream>>>((float4*)y, bnsum, bnsumsq, gamma, beta,
                                     (float4*)smm, rowsum,
                                     (const float4*)colsum, (float4*)smq);
}